// Round 17
// baseline (863.467 us; speedup 1.0000x reference)
//
#include <hip/hip_runtime.h>
#include <cstdint>
#include <cmath>

#define T_TOK 8192
#define DIM   1024
#define HID   2816
#define NE    8
#define ALGN  256
#define NCAP  18432   // 16384 routed rows + 8*256 alignment padding

typedef __attribute__((ext_vector_type(8))) short short8_t;
typedef __attribute__((ext_vector_type(4))) float float4_t;
typedef __attribute__((ext_vector_type(4))) int int4_t;

typedef const __attribute__((address_space(1))) unsigned int gas_uint;
typedef __attribute__((address_space(3))) unsigned int las_uint;

__device__ __forceinline__ unsigned short f2bf(float f) {
  union { float f; uint32_t u; } c; c.f = f;
  const uint32_t u = c.u;
  return (unsigned short)((u + 0x7FFFu + ((u >> 16) & 1u)) >> 16);
}
__device__ __forceinline__ float bf2f(unsigned short h) {
  union { uint32_t u; float f; } c; c.u = ((uint32_t)h) << 16;
  return c.f;
}

__device__ __forceinline__ void gload_lds16(const void* g, void* l) {
  __builtin_amdgcn_global_load_lds((gas_uint*)g, (las_uint*)l, 16, 0, 0);
}

__device__ __forceinline__ float4_t mfma16(short8_t a, short8_t b, float4_t c) {
  return __builtin_amdgcn_mfma_f32_16x16x32_bf16(a, b, c, 0, 0, 0);
}

// convert 8 fp32 (two float4) -> 16B of bf16 in regs
__device__ __forceinline__ int4_t cvt8(const float4 a, const float4 b) {
  unsigned short ob[8];
  ob[0] = f2bf(a.x); ob[1] = f2bf(a.y); ob[2] = f2bf(a.z); ob[3] = f2bf(a.w);
  ob[4] = f2bf(b.x); ob[5] = f2bf(b.y); ob[6] = f2bf(b.z); ob[7] = f2bf(b.w);
  return *(const int4_t*)ob;
}

#define LGKM0_SBAR() do { asm volatile("s_waitcnt lgkmcnt(0)" ::: "memory"); \
                          __builtin_amdgcn_sched_barrier(0); \
                          __builtin_amdgcn_s_barrier(); \
                          asm volatile("" ::: "memory"); } while(0)
#define VMW_BAR(N) do { asm volatile("s_waitcnt vmcnt(" #N ") lgkmcnt(0)" ::: "memory"); \
                        __builtin_amdgcn_sched_barrier(0); \
                        __builtin_amdgcn_s_barrier(); \
                        asm volatile("" ::: "memory"); } while(0)

// ---------------- gating + x fp32->bf16 (fused; 4 tokens/block) ----------------
__global__ __launch_bounds__(256) void gate_kernel(const float* __restrict__ x,
                                                   const float* __restrict__ gwt,
                                                   unsigned short* __restrict__ x_bf,
                                                   int* __restrict__ ids,
                                                   float* __restrict__ wts,
                                                   int* __restrict__ counts) {
  const int w = threadIdx.x >> 6;
  const int l = threadIdx.x & 63;
  const int t = blockIdx.x * 4 + w;
  const float* xr = x + (size_t)t * DIM + l * 16;
  float4 xv[4];
  #pragma unroll
  for (int k = 0; k < 4; ++k) xv[k] = ((const float4*)xr)[k];

  {
    unsigned short ob[16];
    #pragma unroll
    for (int k = 0; k < 4; ++k) {
      ob[k * 4 + 0] = f2bf(xv[k].x); ob[k * 4 + 1] = f2bf(xv[k].y);
      ob[k * 4 + 2] = f2bf(xv[k].z); ob[k * 4 + 3] = f2bf(xv[k].w);
    }
    int4_t* dst = (int4_t*)(x_bf + (size_t)t * DIM + l * 16);
    dst[0] = *(const int4_t*)&ob[0];
    dst[1] = *(const int4_t*)&ob[8];
  }

  float acc[NE];
  #pragma unroll
  for (int e = 0; e < NE; ++e) {
    const float4* gp = (const float4*)(gwt + e * DIM + l * 16);
    float s = 0.0f;
    #pragma unroll
    for (int k = 0; k < 4; ++k) {
      const float4 g = gp[k];
      s += xv[k].x * g.x + xv[k].y * g.y + xv[k].z * g.z + xv[k].w * g.w;
    }
    acc[e] = s;
  }
  #pragma unroll
  for (int e = 0; e < NE; ++e) {
    #pragma unroll
    for (int s = 32; s > 0; s >>= 1) acc[e] += __shfl_xor(acc[e], s);
  }
  if (l == 0) {
    int i0 = 0; float v0 = acc[0];
    #pragma unroll
    for (int e = 1; e < NE; ++e) if (acc[e] > v0) { v0 = acc[e]; i0 = e; }
    int i1 = -1; float v1 = -3.4e38f;
    #pragma unroll
    for (int e = 0; e < NE; ++e) if (e != i0 && acc[e] > v1) { v1 = acc[e]; i1 = e; }
    const float w0 = 1.0f / (1.0f + expf(v1 - v0));  // == softmax-top2-renorm
    ids[t * 2]     = i0;
    ids[t * 2 + 1] = i1;
    wts[t * 2]     = w0;
    wts[t * 2 + 1] = 1.0f - w0;
    atomicAdd(&counts[i0], 1);
    atomicAdd(&counts[i1], 1);
  }
}

// ---------------- per-expert 256-aligned exclusive prefix offsets ----------------
__global__ void offsets_kernel(const int* __restrict__ counts, int* __restrict__ offs) {
  if (threadIdx.x == 0 && blockIdx.x == 0) {
    int o = 0;
    #pragma unroll
    for (int e = 0; e < NE; ++e) { offs[e] = o; o += (counts[e] + ALGN - 1) & ~(ALGN - 1); }
    offs[NE] = o;
  }
}

// ---------------- scatter ----------------
__global__ __launch_bounds__(256) void scatter_kernel(const int* __restrict__ ids,
                                                      const int* __restrict__ offs,
                                                      int* __restrict__ cursor,
                                                      int* __restrict__ rowmap,
                                                      int* __restrict__ tok2slot) {
  const int t = blockIdx.x * blockDim.x + threadIdx.x;
  if (t >= T_TOK) return;
  #pragma unroll
  for (int j = 0; j < 2; ++j) {
    const int e = ids[t * 2 + j];
    const int pos = atomicAdd(&cursor[e], 1);
    const int s = offs[e] + pos;
    rowmap[s] = t;
    tok2slot[t * 2 + j] = s;
  }
}

// =======================================================================
// GEMM1 (r17): weights consumed as FP32 with in-kernel bf16 conversion.
// A (x_bf) via global_load_lds; G/U reg-staged: fp32 loads at tile-top,
// cvt + ds_write after MFMA cluster 1 (T14 issue-early/write-late).
// End-of-tile VMW_BAR(2) counts A-gloads only; lgkm0 drains ds_writes.
// LDS layout/reads identical to r12 (swizzled 128B rows, 0-conflict).
// =======================================================================
__global__ __launch_bounds__(512, 2)
void gemm1_kernel(const unsigned short* __restrict__ xb,
                  const float* __restrict__ wgf,
                  const float* __restrict__ wuf,
                  const int* __restrict__ rowmap,
                  const int* __restrict__ offs,
                  unsigned short* __restrict__ H) {
  extern __shared__ char sm[];
  // A(d): d*32768 (32KB); G(d): 65536+d*16384; U(d): 98304+d*16384; dummy: 131072
  const int bid = blockIdx.x;
  const int swz = (bid & 7) * 198 + (bid >> 3);      // 1584 % 8 == 0 -> bijective
  const int bn = swz / 72, bm = swz % 72;            // bm fastest: weight slice L2-resident per XCD

  const int slot0 = bm * 256;
  if (slot0 >= offs[NE]) return;
  int e = 0;
  while (slot0 >= offs[e + 1]) ++e;
  const float* wgE = wgf + (size_t)e * HID * DIM;
  const float* wuE = wuf + (size_t)e * HID * DIM;
  const int n0 = bn * 128;

  const int tid = threadIdx.x;
  const int w = tid >> 6;
  const int lane = tid & 63;
  const int wm = w >> 2;     // 0..1
  const int wn = w & 3;      // 0..3

  const int g = (lane & 7) ^ ((lane >> 3) & 7);
  const int srow = 8 * w + (lane >> 3);
  const unsigned short* pA[4];
  #pragma unroll
  for (int q = 0; q < 4; ++q)
    pA[q] = xb + (size_t)rowmap[slot0 + q * 64 + srow] * DIM + g * 8;
  const float* pGf[2];
  const float* pUf[2];
  #pragma unroll
  for (int q = 0; q < 2; ++q) {
    pGf[q] = wgE + (size_t)(n0 + q * 64 + srow) * DIM + g * 8;
    pUf[q] = wuE + (size_t)(n0 + q * 64 + srow) * DIM + g * 8;
  }
  char* dummy = sm + 131072;

  const int q16 = (lane >> 4) * 16;
  int soA[8], soB[2];
  #pragma unroll
  for (int mi = 0; mi < 8; ++mi) {
    const int rr = wm * 128 + mi * 16 + (lane & 15);
    soA[mi] = rr * 128 + (q16 ^ ((rr & 7) << 4));
  }
  #pragma unroll
  for (int ni = 0; ni < 2; ++ni) {
    const int rn = wn * 32 + ni * 16 + (lane & 15);
    soB[ni] = rn * 128 + (q16 ^ ((rn & 7) << 4));
  }

  const float4_t z4 = {0.f, 0.f, 0.f, 0.f};
  float4_t accg[8][2], accu[8][2];
  #pragma unroll
  for (int mi = 0; mi < 8; ++mi) { accg[mi][0] = z4; accg[mi][1] = z4; accu[mi][0] = z4; accu[mi][1] = z4; }

  auto stA0 = [&](int t) {
    if (t < 16) {
      char* base = sm + (t & 1) * 32768 + w * 1024;
      gload_lds16(pA[0] + t * 64, base);
      gload_lds16(pA[1] + t * 64, base + 8192);
    } else { gload_lds16(xb, dummy); gload_lds16(xb, dummy); }
  };
  auto stA1 = [&](int t) {
    if (t < 16) {
      char* base = sm + (t & 1) * 32768 + w * 1024;
      gload_lds16(pA[2] + t * 64, base + 16384);
      gload_lds16(pA[3] + t * 64, base + 24576);
    } else { gload_lds16(xb, dummy); gload_lds16(xb, dummy); }
  };
  // fp32 weight reg-load for tile t: 8 float4 (G q0,q1 ; U q0,q1)
  auto ldGU = [&](int t, float4* rg) {
    if (t < 16) {
      #pragma unroll
      for (int q = 0; q < 2; ++q) {
        const float4* pg = (const float4*)(pGf[q] + t * 64);
        rg[q * 2 + 0] = pg[0];
        rg[q * 2 + 1] = pg[1];
        const float4* pu = (const float4*)(pUf[q] + t * 64);
        rg[4 + q * 2 + 0] = pu[0];
        rg[4 + q * 2 + 1] = pu[1];
      }
    }
  };
  // cvt + ds_write to the same swizzled layout gload_lds produced
  auto wrGU = [&](int t, const float4* rg) {
    if (t < 16) {
      const int d2 = t & 1;
      char* gb = sm + 65536 + d2 * 16384 + w * 1024 + lane * 16;
      char* ub = sm + 98304 + d2 * 16384 + w * 1024 + lane * 16;
      *(int4_t*)gb            = cvt8(rg[0], rg[1]);
      *(int4_t*)(gb + 8192)   = cvt8(rg[2], rg[3]);
      *(int4_t*)ub            = cvt8(rg[4], rg[5]);
      *(int4_t*)(ub + 8192)   = cvt8(rg[6], rg[7]);
    }
  };

  float4 rg[8];
  // prologue: tile0 G/U via regs (write immediately), A0/A1(0), A0(1)
  ldGU(0, rg);
  wrGU(0, rg);                 // compiler waits for the 8 reg loads
  stA0(0); stA1(0);            // 4 gloads
  stA0(1);                     // 2 gloads
  VMW_BAR(2);                  // forces A0(0),A1(0); leaves A0(1); lgkm0 drains writes

  for (int T = 0; T < 16; ++T) {
    const int d = T & 1;
    char* Ab = sm + d * 32768;
    char* Gb = sm + 65536 + d * 16384;
    char* Ub = sm + 98304 + d * 16384;
    short8_t a0[8], a1[8], bb[2], cc[2];

    // top: issue next-tile fp32 weight loads (oldest), then A1 gloads
    ldGU(T + 1, rg);
    stA1(T + 1);

    #pragma unroll
    for (int mi = 0; mi < 8; ++mi) a0[mi] = *(const short8_t*)(Ab + soA[mi]);
    bb[0] = *(const short8_t*)(Gb + soB[0]);
    bb[1] = *(const short8_t*)(Gb + soB[1]);
    __builtin_amdgcn_s_setprio(1);
    #pragma unroll
    for (int mi = 0; mi < 8; ++mi) {
      accg[mi][0] = mfma16(a0[mi], bb[0], accg[mi][0]);
      accg[mi][1] = mfma16(a0[mi], bb[1], accg[mi][1]);
    }
    __builtin_amdgcn_s_setprio(0);

    // write-late: cvt + ds_write next-tile G/U (waits only the reg loads)
    wrGU(T + 1, rg);

    cc[0] = *(const short8_t*)(Ub + soB[0]);
    cc[1] = *(const short8_t*)(Ub + soB[1]);
    __builtin_amdgcn_s_setprio(1);
    #pragma unroll
    for (int mi = 0; mi < 8; ++mi) {
      accu[mi][0] = mfma16(a0[mi], cc[0], accu[mi][0]);
      accu[mi][1] = mfma16(a0[mi], cc[1], accu[mi][1]);
    }
    __builtin_amdgcn_s_setprio(0);

    #pragma unroll
    for (int mi = 0; mi < 8; ++mi) a1[mi] = *(const short8_t*)(Ab + (soA[mi] ^ 64));
    bb[0] = *(const short8_t*)(Gb + (soB[0] ^ 64));
    bb[1] = *(const short8_t*)(Gb + (soB[1] ^ 64));
    __builtin_amdgcn_s_setprio(1);
    #pragma unroll
    for (int mi = 0; mi < 8; ++mi) {
      accg[mi][0] = mfma16(a1[mi], bb[0], accg[mi][0]);
      accg[mi][1] = mfma16(a1[mi], bb[1], accg[mi][1]);
    }
    __builtin_amdgcn_s_setprio(0);

    LGKM0_SBAR();   // barrier 1: all waves' buffer-d A reads done

    cc[0] = *(const short8_t*)(Ub + (soB[0] ^ 64));
    cc[1] = *(const short8_t*)(Ub + (soB[1] ^ 64));
    stA0(T + 2);
    // barrier 2: queue = [A1(T+1)x2, A0(T+2)x2] -> forces A1(T+1)
    // (A0(T+1) forced at previous tile's barrier); lgkm0 drains ds_writes.
    VMW_BAR(2);
    __builtin_amdgcn_s_setprio(1);
    #pragma unroll
    for (int mi = 0; mi < 8; ++mi) {
      accu[mi][0] = mfma16(a1[mi], cc[0], accu[mi][0]);
      accu[mi][1] = mfma16(a1[mi], cc[1], accu[mi][1]);
    }
    __builtin_amdgcn_s_setprio(0);
  }

  // ---- epilogue: silu(g)*u -> LDS bounce -> coalesced dwordx4 stores ----
  #pragma unroll
  for (int mi = 0; mi < 8; ++mi) {
    #pragma unroll
    for (int j = 0; j < 4; ++j) {
      const int row = wm * 128 + mi * 16 + ((lane >> 4) * 4) + j;
      #pragma unroll
      for (int ni = 0; ni < 2; ++ni) {
        const int col = wn * 32 + ni * 16 + (lane & 15);
        const float gg = accg[mi][ni][j];
        const float uu = accu[mi][ni][j];
        const float h = (gg / (1.0f + __expf(-gg))) * uu;
        *(unsigned short*)(sm + row * 256 + ((col * 2) ^ ((row & 3) << 4))) = f2bf(h);
      }
    }
  }
  LGKM0_SBAR();
  const int gran = tid & 15;
  #pragma unroll
  for (int p = 0; p < 8; ++p) {
    const int row = p * 32 + (tid >> 4);
    const int4_t v = *(const int4_t*)(sm + row * 256 + ((gran * 16) ^ ((row & 3) << 4)));
    *(int4_t*)(H + (size_t)(slot0 + row) * HID + n0 + gran * 8) = v;
  }
}

// =======================================================================
// GEMM2 (r17): wd consumed as FP32 (reg-staged cvt), H via global_load_lds.
// 256 x 128, BK=64, 8 waves, TRIPLE buffer, ONE VMW_BAR(4) per K-tile.
// =======================================================================
__global__ __launch_bounds__(512, 2)
void gemm2_kernel(const unsigned short* __restrict__ Hb,
                  const float* __restrict__ wdf,
                  const int* __restrict__ offs,
                  unsigned short* __restrict__ Yb) {
  extern __shared__ char sm[];
  // buffer b: A @ b*49152 (32KB), B @ b*49152+32768 (16KB); dummy @ 147456
  const int bid = blockIdx.x;
  const int swz = (bid & 7) * 72 + (bid >> 3);       // 576 % 8 == 0
  const int bm = swz >> 3, bn = swz & 7;             // bn fastest: A(H)-reuse in L2

  const int slot0 = bm * 256;
  if (slot0 >= offs[NE]) return;
  int e = 0;
  while (slot0 >= offs[e + 1]) ++e;
  const float* wdE = wdf + (size_t)e * DIM * HID;
  const int n0 = bn * 128;

  const int tid = threadIdx.x;
  const int w = tid >> 6;
  const int lane = tid & 63;
  const int wm = w >> 2;
  const int wn = w & 3;

  const int g = (lane & 7) ^ ((lane >> 3) & 7);
  const int srow = 8 * w + (lane >> 3);
  const unsigned short* pA[4];
  #pragma unroll
  for (int q = 0; q < 4; ++q)
    pA[q] = Hb + (size_t)(slot0 + q * 64 + srow) * HID + g * 8;
  const float* pBf[2];
  #pragma unroll
  for (int q = 0; q < 2; ++q)
    pBf[q] = wdE + (size_t)(n0 + q * 64 + srow) * HID + g * 8;
  char* dummy = sm + 147456;

  const int q16 = (lane >> 4) * 16;
  int soA[8], soB[2];
  #pragma unroll
  for (int mi = 0; mi < 8; ++mi) {
    const int rr = wm * 128 + mi * 16 + (lane & 15);
    soA[mi] = rr * 128 + (q16 ^ ((rr & 7) << 4));
  }
  #pragma unroll
  for (int ni = 0; ni < 2; ++ni) {
    const int rn = wn * 32 + ni * 16 + (lane & 15);
    soB[ni] = rn * 128 + (q16 ^ ((rn & 7) << 4));
  }

  const float4_t z4 = {0.f, 0.f, 0.f, 0.f};
  float4_t acc[8][2];
  #pragma unroll
  for (int mi = 0; mi < 8; ++mi) { acc[mi][0] = z4; acc[mi][1] = z4; }

  auto stA01 = [&](int t, int bf) {
    if (t < 44) {
      char* base = sm + bf * 49152 + w * 1024;
      gload_lds16(pA[0] + t * 64, base);
      gload_lds16(pA[1] + t * 64, base + 8192);
      gload_lds16(pA[2] + t * 64, base + 16384);
      gload_lds16(pA[3] + t * 64, base + 24576);
    } else {
      gload_lds16(Hb, dummy); gload_lds16(Hb, dummy);
      gload_lds16(Hb, dummy); gload_lds16(Hb, dummy);
    }
  };
  auto ldB = [&](int t, float4* rb) {
    if (t < 44) {
      #pragma unroll
      for (int q = 0; q < 2; ++q) {
        const float4* pb = (const float4*)(pBf[q] + t * 64);
        rb[q * 2 + 0] = pb[0];
        rb[q * 2 + 1] = pb[1];
      }
    }
  };
  auto wrB = [&](int t, int bf, const float4* rb) {
    if (t < 44) {
      char* base = sm + bf * 49152 + 32768 + w * 1024 + lane * 16;
      *(int4_t*)base          = cvt8(rb[0], rb[1]);
      *(int4_t*)(base + 8192) = cvt8(rb[2], rb[3]);
    }
  };

  float4 rb[4];
  // prologue: B(0),B(1) via regs (written immediately); A(0),A(1) gloads
  ldB(0, rb); wrB(0, 0, rb);
  ldB(1, rb); wrB(1, 1, rb);
  stA01(0, 0); stA01(1, 1);
  VMW_BAR(4);                  // forces A(0); leaves A(1); lgkm0 drains B writes

  int b = 0;
  for (int T = 0; T < 44; ++T) {
    char* Ab = sm + b * 49152;
    char* Bb = Ab + 32768;
    const int b2 = (b >= 1) ? b - 1 : 2;   // (b+2)%3
    short8_t af0[8], af1[8], bbv[2], cc[2];

    ldB(T + 2, rb);            // 4 fp32 reg loads (oldest)
    stA01(T + 2, b2);          // 4 gloads

    #pragma unroll
    for (int mi = 0; mi < 8; ++mi) {
      af0[mi] = *(const short8_t*)(Ab + soA[mi]);
      af1[mi] = *(const short8_t*)(Ab + (soA[mi] ^ 64));
    }
    bbv[0] = *(const short8_t*)(Bb + soB[0]);
    bbv[1] = *(const short8_t*)(Bb + soB[1]);
    cc[0] = *(const short8_t*)(Bb + (soB[0] ^ 64));
    cc[1] = *(const short8_t*)(Bb + (soB[1] ^ 64));

    __builtin_amdgcn_s_setprio(1);
    #pragma unroll
    for (int mi = 0; mi < 8; ++mi) {
      acc[mi][0] = mfma16(af0[mi], bbv[0], acc[mi][0]);
      acc[mi][1] = mfma16(af0[mi], bbv[1], acc[mi][1]);
    }
    __builtin_amdgcn_s_setprio(0);

    wrB(T + 2, b2, rb);        // cvt + 2 ds_writes (waits reg loads only)

    __builtin_amdgcn_s_setprio(1);
    #pragma unroll
    for (int mi = 0; mi < 8; ++mi) {
      acc[mi][0] = mfma16(af1[mi], cc[0], acc[mi][0]);
      acc[mi][1] = mfma16(af1[mi], cc[1], acc[mi][1]);
    }
    __builtin_amdgcn_s_setprio(0);

    // queue: [A(T+1)x4 (issued T-1), A(T+2)x4] -> forces A(T+1)
    VMW_BAR(4);
    b = (b == 2) ? 0 : b + 1;
  }

  #pragma unroll
  for (int mi = 0; mi < 8; ++mi) {
    #pragma unroll
    for (int j = 0; j < 4; ++j) {
      const int row = wm * 128 + mi * 16 + ((lane >> 4) * 4) + j;
      #pragma unroll
      for (int ni = 0; ni < 2; ++ni) {
        const int col = wn * 32 + ni * 16 + (lane & 15);
        *(unsigned short*)(sm + row * 256 + ((col * 2) ^ ((row & 3) << 4))) = f2bf(acc[mi][ni][j]);
      }
    }
  }
  LGKM0_SBAR();
  const int gran = tid & 15;
  #pragma unroll
  for (int p = 0; p < 8; ++p) {
    const int row = p * 32 + (tid >> 4);
    const int4_t v = *(const int4_t*)(sm + row * 256 + ((gran * 16) ^ ((row & 3) << 4)));
    *(int4_t*)(Yb + (size_t)(slot0 + row) * DIM + n0 + gran * 8) = v;
  }
}

// ---------------- combine: y[t] = w0*Y[s0] + w1*Y[s1] ----------------
__global__ __launch_bounds__(256) void combine_kernel(const unsigned short* __restrict__ Yb,
                                                      const int* __restrict__ tok2slot,
                                                      const float* __restrict__ wts,
                                                      float* __restrict__ y) {
  const int t = blockIdx.x;
  const int c = threadIdx.x * 4;
  const int s0 = tok2slot[t * 2], s1 = tok2slot[t * 2 + 1];
  const float w0 = wts[t * 2], w1 = wts[t * 2 + 1];
  const ushort4 a = *(const ushort4*)(Yb + (size_t)s0 * DIM + c);
  const ushort4 b = *(const ushort4*)(Yb + (size_t)s1 * DIM + c);
  float4 o;
  o.x = w0 * bf2f(a.x) + w1 * bf2f(b.x);
  o.y = w0 * bf2f(a.y) + w1 * bf2f(b.y);
  o.z = w0 * bf2f(a.z) + w1 * bf2f(b.z);
  o.w = w0 * bf2f(a.w) + w1 * bf2f(b.w);
  *(float4*)(y + (size_t)t * DIM + c) = o;
}

extern "C" void kernel_launch(void* const* d_in, const int* in_sizes, int n_in,
                              void* d_out, int out_size, void* d_ws, size_t ws_size,
                              hipStream_t stream) {
  (void)in_sizes; (void)n_in; (void)ws_size; (void)out_size;
  const float* x   = (const float*)d_in[0];
  const float* gwt = (const float*)d_in[1];
  const float* wg  = (const float*)d_in[2];
  const float* wu  = (const float*)d_in[3];
  const float* wd  = (const float*)d_in[4];
  float* y = (float*)d_out;

  char* ws = (char*)d_ws;
  size_t o = 0;
  auto alloc = [&](size_t bytes) -> char* {
    o = (o + 255) & ~(size_t)255;
    char* pp = ws + o;
    o += bytes;
    return pp;
  };
  unsigned short* x_bf  = (unsigned short*)alloc((size_t)T_TOK * DIM * 2);
  unsigned short* Hbuf  = (unsigned short*)alloc((size_t)NCAP * HID * 2);
  unsigned short* Ybuf  = (unsigned short*)alloc((size_t)NCAP * DIM * 2);
  int*   ids      = (int*)alloc((size_t)T_TOK * 2 * 4);
  float* wts      = (float*)alloc((size_t)T_TOK * 2 * 4);
  int*   tok2slot = (int*)alloc((size_t)T_TOK * 2 * 4);
  // zero-needed region starts here:
  int*   rowmap = (int*)alloc((size_t)NCAP * 4);
  int*   counts = (int*)alloc(64);
  int*   offs   = (int*)alloc(64);
  int*   cursor = (int*)alloc(64);

  hipMemsetAsync(rowmap, 0, (size_t)((ws + o) - (char*)rowmap), stream);

  hipFuncSetAttribute((const void*)gemm1_kernel, hipFuncAttributeMaxDynamicSharedMemorySize, 132096);
  hipFuncSetAttribute((const void*)gemm2_kernel, hipFuncAttributeMaxDynamicSharedMemorySize, 148480);

  gate_kernel<<<T_TOK / 4, 256, 0, stream>>>(x, gwt, x_bf, ids, wts, counts);
  offsets_kernel<<<1, 1, 0, stream>>>(counts, offs);
  scatter_kernel<<<T_TOK / 256, 256, 0, stream>>>(ids, offs, cursor, rowmap, tok2slot);

  gemm1_kernel<<<dim3((NCAP / 256) * 22), 512, 132096, stream>>>(x_bf, wg, wu, rowmap, offs, Hbuf);
  gemm2_kernel<<<dim3((NCAP / 256) * 8), 512, 148480, stream>>>(Hbuf, wd, offs, Ybuf);
  combine_kernel<<<T_TOK, 256, 0, stream>>>(Ybuf, tok2slot, wts, y);
}

// Round 18
// 642.754 us; speedup vs baseline: 1.3434x; 1.3434x over previous
//
#include <hip/hip_runtime.h>
#include <cstdint>
#include <cmath>

#define T_TOK 8192
#define DIM   1024
#define HID   2816
#define NE    8
#define ALGN  256
#define NCAP  18432   // 16384 routed rows + 8*256 alignment padding

typedef __attribute__((ext_vector_type(8))) short short8_t;
typedef __attribute__((ext_vector_type(4))) float float4_t;
typedef __attribute__((ext_vector_type(4))) int int4_t;
typedef __attribute__((ext_vector_type(4))) float f4_t;

typedef const __attribute__((address_space(1))) unsigned int gas_uint;
typedef __attribute__((address_space(3))) unsigned int las_uint;

__device__ __forceinline__ unsigned short f2bf(float f) {
  union { float f; uint32_t u; } c; c.f = f;
  const uint32_t u = c.u;
  return (unsigned short)((u + 0x7FFFu + ((u >> 16) & 1u)) >> 16);
}
__device__ __forceinline__ float bf2f(unsigned short h) {
  union { uint32_t u; float f; } c; c.u = ((uint32_t)h) << 16;
  return c.f;
}

__device__ __forceinline__ void gload_lds16(const void* g, void* l) {
  __builtin_amdgcn_global_load_lds((gas_uint*)g, (las_uint*)l, 16, 0, 0);
}

__device__ __forceinline__ float4_t mfma16(short8_t a, short8_t b, float4_t c) {
  return __builtin_amdgcn_mfma_f32_16x16x32_bf16(a, b, c, 0, 0, 0);
}

#define LGKM0_SBAR() do { asm volatile("s_waitcnt lgkmcnt(0)" ::: "memory"); \
                          __builtin_amdgcn_sched_barrier(0); \
                          __builtin_amdgcn_s_barrier(); \
                          asm volatile("" ::: "memory"); } while(0)
#define VMW_BAR(N) do { asm volatile("s_waitcnt vmcnt(" #N ") lgkmcnt(0)" ::: "memory"); \
                        __builtin_amdgcn_sched_barrier(0); \
                        __builtin_amdgcn_s_barrier(); \
                        asm volatile("" ::: "memory"); } while(0)

// ---------------- fused cvt(weights) + gate(+x cvt), role-INTERLEAVED ----------------
// 4096 blocks: odd bid -> gate (2048 blocks x 4 tokens); even bid -> cvt
// (2048 blocks, flattened grid-stride over all 3 weight tensors, NT ld/st).
#define NW8 ((size_t)NE * HID * DIM / 8)   // 2,883,584 groups of 8 per tensor
#define CVT_BLKS 2048

__global__ __launch_bounds__(256) void cvtgate_kernel(
    const float* __restrict__ wg, const float* __restrict__ wu,
    const float* __restrict__ wd, const float* __restrict__ x,
    const float* __restrict__ gwt,
    unsigned short* __restrict__ wg_bf, unsigned short* __restrict__ wu_bf,
    unsigned short* __restrict__ wd_bf, unsigned short* __restrict__ x_bf,
    int* __restrict__ ids, float* __restrict__ wts, int* __restrict__ counts) {
  const int bid = blockIdx.x;
  if (bid & 1) {
    // ---------------- gate path ----------------
    const int w = threadIdx.x >> 6;
    const int l = threadIdx.x & 63;
    const int t = (bid >> 1) * 4 + w;      // < 8192
    const float* xr = x + (size_t)t * DIM + l * 16;
    float4 xv[4];
    #pragma unroll
    for (int k = 0; k < 4; ++k) xv[k] = ((const float4*)xr)[k];

    {
      unsigned short ob[16];
      #pragma unroll
      for (int k = 0; k < 4; ++k) {
        ob[k * 4 + 0] = f2bf(xv[k].x); ob[k * 4 + 1] = f2bf(xv[k].y);
        ob[k * 4 + 2] = f2bf(xv[k].z); ob[k * 4 + 3] = f2bf(xv[k].w);
      }
      int4_t* dst = (int4_t*)(x_bf + (size_t)t * DIM + l * 16);
      dst[0] = *(const int4_t*)&ob[0];
      dst[1] = *(const int4_t*)&ob[8];
    }

    float acc[NE];
    #pragma unroll
    for (int e = 0; e < NE; ++e) {
      const float4* gp = (const float4*)(gwt + e * DIM + l * 16);
      float s = 0.0f;
      #pragma unroll
      for (int k = 0; k < 4; ++k) {
        const float4 g = gp[k];
        s += xv[k].x * g.x + xv[k].y * g.y + xv[k].z * g.z + xv[k].w * g.w;
      }
      acc[e] = s;
    }
    #pragma unroll
    for (int e = 0; e < NE; ++e) {
      #pragma unroll
      for (int s = 32; s > 0; s >>= 1) acc[e] += __shfl_xor(acc[e], s);
    }
    if (l == 0) {
      int i0 = 0; float v0 = acc[0];
      #pragma unroll
      for (int e = 1; e < NE; ++e) if (acc[e] > v0) { v0 = acc[e]; i0 = e; }
      int i1 = -1; float v1 = -3.4e38f;
      #pragma unroll
      for (int e = 0; e < NE; ++e) if (e != i0 && acc[e] > v1) { v1 = acc[e]; i1 = e; }
      const float w0 = 1.0f / (1.0f + expf(v1 - v0));  // == softmax-top2-renorm
      ids[t * 2]     = i0;
      ids[t * 2 + 1] = i1;
      wts[t * 2]     = w0;
      wts[t * 2 + 1] = 1.0f - w0;
      atomicAdd(&counts[i0], 1);
      atomicAdd(&counts[i1], 1);
    }
  } else {
    // ---------------- weight cvt path (flattened over 3 tensors) ----------------
    const size_t c = (size_t)(bid >> 1);
    const size_t stride = (size_t)CVT_BLKS * 256;
    const size_t G = 3 * NW8;
    for (size_t i = c * 256 + threadIdx.x; i < G; i += stride) {
      const float* s; unsigned short* d; size_t j;
      if (i < NW8)          { s = wg; d = wg_bf; j = i; }
      else if (i < 2 * NW8) { s = wu; d = wu_bf; j = i - NW8; }
      else                  { s = wd; d = wd_bf; j = i - 2 * NW8; }
      const f4_t v0 = __builtin_nontemporal_load((const f4_t*)s + 2 * j);
      const f4_t v1 = __builtin_nontemporal_load((const f4_t*)s + 2 * j + 1);
      unsigned short ob[8];
      #pragma unroll
      for (int k = 0; k < 4; ++k) { ob[k] = f2bf(v0[k]); ob[4 + k] = f2bf(v1[k]); }
      __builtin_nontemporal_store(*(const int4_t*)ob, (int4_t*)(d + j * 8));
    }
  }
}

// ---------------- per-expert 256-aligned exclusive prefix offsets ----------------
__global__ void offsets_kernel(const int* __restrict__ counts, int* __restrict__ offs) {
  if (threadIdx.x == 0 && blockIdx.x == 0) {
    int o = 0;
    #pragma unroll
    for (int e = 0; e < NE; ++e) { offs[e] = o; o += (counts[e] + ALGN - 1) & ~(ALGN - 1); }
    offs[NE] = o;
  }
}

// ---------------- scatter ----------------
__global__ __launch_bounds__(256) void scatter_kernel(const int* __restrict__ ids,
                                                      const int* __restrict__ offs,
                                                      int* __restrict__ cursor,
                                                      int* __restrict__ rowmap,
                                                      int* __restrict__ tok2slot) {
  const int t = blockIdx.x * blockDim.x + threadIdx.x;
  if (t >= T_TOK) return;
  #pragma unroll
  for (int j = 0; j < 2; ++j) {
    const int e = ids[t * 2 + j];
    const int pos = atomicAdd(&cursor[e], 1);
    const int s = offs[e] + pos;
    rowmap[s] = t;
    tok2slot[t * 2 + j] = s;
  }
}

// =======================================================================
// GEMM1 (r12/r16 frozen): H = silu(X wg^T) * (X wu^T)
// 256 x (128G || 128U), BK=64, 8 waves (2Mx4N). 2 barriers/K-tile;
// VMW_BAR(2) once per tile. bm-fastest XCD swizzle (weights L2-resident).
// =======================================================================
__global__ __launch_bounds__(512, 2)
void gemm1_kernel(const unsigned short* __restrict__ xb,
                  const unsigned short* __restrict__ wgb,
                  const unsigned short* __restrict__ wub,
                  const int* __restrict__ rowmap,
                  const int* __restrict__ offs,
                  unsigned short* __restrict__ H) {
  extern __shared__ char sm[];
  const int bid = blockIdx.x;
  const int swz = (bid & 7) * 198 + (bid >> 3);      // 1584 % 8 == 0 -> bijective
  const int bn = swz / 72, bm = swz % 72;            // bm fastest: weights L2-resident per XCD

  const int slot0 = bm * 256;
  if (slot0 >= offs[NE]) return;
  int e = 0;
  while (slot0 >= offs[e + 1]) ++e;
  const unsigned short* wgE = wgb + (size_t)e * HID * DIM;
  const unsigned short* wuE = wub + (size_t)e * HID * DIM;
  const int n0 = bn * 128;

  const int tid = threadIdx.x;
  const int w = tid >> 6;
  const int lane = tid & 63;
  const int wm = w >> 2;     // 0..1
  const int wn = w & 3;      // 0..3

  const int g = (lane & 7) ^ ((lane >> 3) & 7);
  const int srow = 8 * w + (lane >> 3);
  const unsigned short* pA[4];
  #pragma unroll
  for (int q = 0; q < 4; ++q)
    pA[q] = xb + (size_t)rowmap[slot0 + q * 64 + srow] * DIM + g * 8;
  const unsigned short* pG[2];
  const unsigned short* pU[2];
  #pragma unroll
  for (int q = 0; q < 2; ++q) {
    pG[q] = wgE + (size_t)(n0 + q * 64 + srow) * DIM + g * 8;
    pU[q] = wuE + (size_t)(n0 + q * 64 + srow) * DIM + g * 8;
  }
  char* dummy = sm + 131072;

  const int q16 = (lane >> 4) * 16;
  int soA[8], soB[2];
  #pragma unroll
  for (int mi = 0; mi < 8; ++mi) {
    const int rr = wm * 128 + mi * 16 + (lane & 15);
    soA[mi] = rr * 128 + (q16 ^ ((rr & 7) << 4));
  }
  #pragma unroll
  for (int ni = 0; ni < 2; ++ni) {
    const int rn = wn * 32 + ni * 16 + (lane & 15);
    soB[ni] = rn * 128 + (q16 ^ ((rn & 7) << 4));
  }

  const float4_t z4 = {0.f, 0.f, 0.f, 0.f};
  float4_t accg[8][2], accu[8][2];
  #pragma unroll
  for (int mi = 0; mi < 8; ++mi) { accg[mi][0] = z4; accg[mi][1] = z4; accu[mi][0] = z4; accu[mi][1] = z4; }

  auto stA0 = [&](int t) {
    if (t < 16) {
      char* base = sm + (t & 1) * 32768 + w * 1024;
      gload_lds16(pA[0] + t * 64, base);
      gload_lds16(pA[1] + t * 64, base + 8192);
    } else { gload_lds16(xb, dummy); gload_lds16(xb, dummy); }
  };
  auto stA1 = [&](int t) {
    if (t < 16) {
      char* base = sm + (t & 1) * 32768 + w * 1024;
      gload_lds16(pA[2] + t * 64, base + 16384);
      gload_lds16(pA[3] + t * 64, base + 24576);
    } else { gload_lds16(xb, dummy); gload_lds16(xb, dummy); }
  };
  auto stG = [&](int t) {
    if (t < 16) {
      char* base = sm + 65536 + (t & 1) * 16384 + w * 1024;
      gload_lds16(pG[0] + t * 64, base);
      gload_lds16(pG[1] + t * 64, base + 8192);
    } else { gload_lds16(xb, dummy); gload_lds16(xb, dummy); }
  };
  auto stU = [&](int t) {
    if (t < 16) {
      char* base = sm + 98304 + (t & 1) * 16384 + w * 1024;
      gload_lds16(pU[0] + t * 64, base);
      gload_lds16(pU[1] + t * 64, base + 8192);
    } else { gload_lds16(xb, dummy); gload_lds16(xb, dummy); }
  };

  stA0(0); stA1(0); stG(0); stU(0); stA0(1);
  VMW_BAR(2);

  for (int T = 0; T < 16; ++T) {
    const int d = T & 1;
    char* Ab = sm + d * 32768;
    char* Gb = sm + 65536 + d * 16384;
    char* Ub = sm + 98304 + d * 16384;
    short8_t a0[8], a1[8], bb[2], cc[2];

    #pragma unroll
    for (int mi = 0; mi < 8; ++mi) a0[mi] = *(const short8_t*)(Ab + soA[mi]);
    bb[0] = *(const short8_t*)(Gb + soB[0]);
    bb[1] = *(const short8_t*)(Gb + soB[1]);
    stA1(T + 1); stG(T + 1);
    __builtin_amdgcn_s_setprio(1);
    #pragma unroll
    for (int mi = 0; mi < 8; ++mi) {
      accg[mi][0] = mfma16(a0[mi], bb[0], accg[mi][0]);
      accg[mi][1] = mfma16(a0[mi], bb[1], accg[mi][1]);
    }
    __builtin_amdgcn_s_setprio(0);

    cc[0] = *(const short8_t*)(Ub + soB[0]);
    cc[1] = *(const short8_t*)(Ub + soB[1]);
    stU(T + 1);
    __builtin_amdgcn_s_setprio(1);
    #pragma unroll
    for (int mi = 0; mi < 8; ++mi) {
      accu[mi][0] = mfma16(a0[mi], cc[0], accu[mi][0]);
      accu[mi][1] = mfma16(a0[mi], cc[1], accu[mi][1]);
    }
    __builtin_amdgcn_s_setprio(0);

    #pragma unroll
    for (int mi = 0; mi < 8; ++mi) a1[mi] = *(const short8_t*)(Ab + (soA[mi] ^ 64));
    bb[0] = *(const short8_t*)(Gb + (soB[0] ^ 64));
    bb[1] = *(const short8_t*)(Gb + (soB[1] ^ 64));
    __builtin_amdgcn_s_setprio(1);
    #pragma unroll
    for (int mi = 0; mi < 8; ++mi) {
      accg[mi][0] = mfma16(a1[mi], bb[0], accg[mi][0]);
      accg[mi][1] = mfma16(a1[mi], bb[1], accg[mi][1]);
    }
    __builtin_amdgcn_s_setprio(0);

    LGKM0_SBAR();   // barrier 1: all waves' buffer-d A reads done

    cc[0] = *(const short8_t*)(Ub + (soB[0] ^ 64));
    cc[1] = *(const short8_t*)(Ub + (soB[1] ^ 64));
    stA0(T + 2);
    VMW_BAR(2);     // barrier 2: forces all tile-(T+1) data, leaves A0(T+2)
    __builtin_amdgcn_s_setprio(1);
    #pragma unroll
    for (int mi = 0; mi < 8; ++mi) {
      accu[mi][0] = mfma16(a1[mi], cc[0], accu[mi][0]);
      accu[mi][1] = mfma16(a1[mi], cc[1], accu[mi][1]);
    }
    __builtin_amdgcn_s_setprio(0);
  }

  #pragma unroll
  for (int mi = 0; mi < 8; ++mi) {
    #pragma unroll
    for (int j = 0; j < 4; ++j) {
      const int row = wm * 128 + mi * 16 + ((lane >> 4) * 4) + j;
      #pragma unroll
      for (int ni = 0; ni < 2; ++ni) {
        const int col = wn * 32 + ni * 16 + (lane & 15);
        const float gg = accg[mi][ni][j];
        const float uu = accu[mi][ni][j];
        const float h = (gg / (1.0f + __expf(-gg))) * uu;
        *(unsigned short*)(sm + row * 256 + ((col * 2) ^ ((row & 3) << 4))) = f2bf(h);
      }
    }
  }
  LGKM0_SBAR();
  const int gran = tid & 15;
  #pragma unroll
  for (int p = 0; p < 8; ++p) {
    const int row = p * 32 + (tid >> 4);
    const int4_t v = *(const int4_t*)(sm + row * 256 + ((gran * 16) ^ ((row & 3) << 4)));
    *(int4_t*)(H + (size_t)(slot0 + row) * HID + n0 + gran * 8) = v;
  }
}

// =======================================================================
// GEMM2 (r12/r16 frozen): Ybuf[slot, 0:1024] = H wd^T (bf16 per-slot)
// 256 x 128, BK=64, 8 waves, TRIPLE buffer, ONE barrier per K-tile.
// =======================================================================
__global__ __launch_bounds__(512, 2)
void gemm2_kernel(const unsigned short* __restrict__ Hb,
                  const unsigned short* __restrict__ wdb,
                  const int* __restrict__ offs,
                  unsigned short* __restrict__ Yb) {
  extern __shared__ char sm[];
  const int bid = blockIdx.x;
  const int swz = (bid & 7) * 72 + (bid >> 3);       // 576 % 8 == 0
  const int bm = swz >> 3, bn = swz & 7;             // bn fastest: A(H)-reuse in L2

  const int slot0 = bm * 256;
  if (slot0 >= offs[NE]) return;
  int e = 0;
  while (slot0 >= offs[e + 1]) ++e;
  const unsigned short* wdE = wdb + (size_t)e * DIM * HID;
  const int n0 = bn * 128;

  const int tid = threadIdx.x;
  const int w = tid >> 6;
  const int lane = tid & 63;
  const int wm = w >> 2;
  const int wn = w & 3;

  const int g = (lane & 7) ^ ((lane >> 3) & 7);
  const int srow = 8 * w + (lane >> 3);
  const unsigned short* pA[4];
  #pragma unroll
  for (int q = 0; q < 4; ++q)
    pA[q] = Hb + (size_t)(slot0 + q * 64 + srow) * HID + g * 8;
  const unsigned short* pB[2];
  #pragma unroll
  for (int q = 0; q < 2; ++q)
    pB[q] = wdE + (size_t)(n0 + q * 64 + srow) * HID + g * 8;
  char* dummy = sm + 147456;

  const int q16 = (lane >> 4) * 16;
  int soA[8], soB[2];
  #pragma unroll
  for (int mi = 0; mi < 8; ++mi) {
    const int rr = wm * 128 + mi * 16 + (lane & 15);
    soA[mi] = rr * 128 + (q16 ^ ((rr & 7) << 4));
  }
  #pragma unroll
  for (int ni = 0; ni < 2; ++ni) {
    const int rn = wn * 32 + ni * 16 + (lane & 15);
    soB[ni] = rn * 128 + (q16 ^ ((rn & 7) << 4));
  }

  const float4_t z4 = {0.f, 0.f, 0.f, 0.f};
  float4_t acc[8][2];
  #pragma unroll
  for (int mi = 0; mi < 8; ++mi) { acc[mi][0] = z4; acc[mi][1] = z4; }

  auto stA01 = [&](int t, int bf) {
    if (t < 44) {
      char* base = sm + bf * 49152 + w * 1024;
      gload_lds16(pA[0] + t * 64, base);
      gload_lds16(pA[1] + t * 64, base + 8192);
      gload_lds16(pA[2] + t * 64, base + 16384);
      gload_lds16(pA[3] + t * 64, base + 24576);
    } else {
      gload_lds16(Hb, dummy); gload_lds16(Hb, dummy);
      gload_lds16(Hb, dummy); gload_lds16(Hb, dummy);
    }
  };
  auto stB = [&](int t, int bf) {
    if (t < 44) {
      char* base = sm + bf * 49152 + 32768 + w * 1024;
      gload_lds16(pB[0] + t * 64, base);
      gload_lds16(pB[1] + t * 64, base + 8192);
    } else { gload_lds16(Hb, dummy); gload_lds16(Hb, dummy); }
  };

  stA01(0, 0); stB(0, 0); stA01(1, 1); stB(1, 1);
  VMW_BAR(6);

  int b = 0;
  for (int T = 0; T < 44; ++T) {
    char* Ab = sm + b * 49152;
    char* Bb = Ab + 32768;
    const int b2 = (b >= 1) ? b - 1 : 2;   // (b+2)%3
    short8_t af0[8], af1[8], bb[2], cc[2];

    #pragma unroll
    for (int mi = 0; mi < 8; ++mi) {
      af0[mi] = *(const short8_t*)(Ab + soA[mi]);
      af1[mi] = *(const short8_t*)(Ab + (soA[mi] ^ 64));
    }
    bb[0] = *(const short8_t*)(Bb + soB[0]);
    bb[1] = *(const short8_t*)(Bb + soB[1]);
    cc[0] = *(const short8_t*)(Bb + (soB[0] ^ 64));
    cc[1] = *(const short8_t*)(Bb + (soB[1] ^ 64));
    stA01(T + 2, b2);
    stB(T + 2, b2);
    __builtin_amdgcn_s_setprio(1);
    #pragma unroll
    for (int mi = 0; mi < 8; ++mi) {
      acc[mi][0] = mfma16(af0[mi], bb[0], acc[mi][0]);
      acc[mi][1] = mfma16(af0[mi], bb[1], acc[mi][1]);
    }
    #pragma unroll
    for (int mi = 0; mi < 8; ++mi) {
      acc[mi][0] = mfma16(af1[mi], cc[0], acc[mi][0]);
      acc[mi][1] = mfma16(af1[mi], cc[1], acc[mi][1]);
    }
    __builtin_amdgcn_s_setprio(0);
    VMW_BAR(6);
    b = (b == 2) ? 0 : b + 1;
  }

  #pragma unroll
  for (int mi = 0; mi < 8; ++mi) {
    #pragma unroll
    for (int j = 0; j < 4; ++j) {
      const int row = wm * 128 + mi * 16 + ((lane >> 4) * 4) + j;
      #pragma unroll
      for (int ni = 0; ni < 2; ++ni) {
        const int col = wn * 32 + ni * 16 + (lane & 15);
        *(unsigned short*)(sm + row * 256 + ((col * 2) ^ ((row & 3) << 4))) = f2bf(acc[mi][ni][j]);
      }
    }
  }
  LGKM0_SBAR();
  const int gran = tid & 15;
  #pragma unroll
  for (int p = 0; p < 8; ++p) {
    const int row = p * 32 + (tid >> 4);
    const int4_t v = *(const int4_t*)(sm + row * 256 + ((gran * 16) ^ ((row & 3) << 4)));
    *(int4_t*)(Yb + (size_t)(slot0 + row) * DIM + n0 + gran * 8) = v;
  }
}

// ---------------- combine: y[t] = w0*Y[s0] + w1*Y[s1] ----------------
__global__ __launch_bounds__(256) void combine_kernel(const unsigned short* __restrict__ Yb,
                                                      const int* __restrict__ tok2slot,
                                                      const float* __restrict__ wts,
                                                      float* __restrict__ y) {
  const int t = blockIdx.x;
  const int c = threadIdx.x * 4;
  const int s0 = tok2slot[t * 2], s1 = tok2slot[t * 2 + 1];
  const float w0 = wts[t * 2], w1 = wts[t * 2 + 1];
  const ushort4 a = *(const ushort4*)(Yb + (size_t)s0 * DIM + c);
  const ushort4 b = *(const ushort4*)(Yb + (size_t)s1 * DIM + c);
  float4 o;
  o.x = w0 * bf2f(a.x) + w1 * bf2f(b.x);
  o.y = w0 * bf2f(a.y) + w1 * bf2f(b.y);
  o.z = w0 * bf2f(a.z) + w1 * bf2f(b.z);
  o.w = w0 * bf2f(a.w) + w1 * bf2f(b.w);
  *(float4*)(y + (size_t)t * DIM + c) = o;
}

extern "C" void kernel_launch(void* const* d_in, const int* in_sizes, int n_in,
                              void* d_out, int out_size, void* d_ws, size_t ws_size,
                              hipStream_t stream) {
  (void)in_sizes; (void)n_in; (void)ws_size; (void)out_size;
  const float* x   = (const float*)d_in[0];
  const float* gwt = (const float*)d_in[1];
  const float* wg  = (const float*)d_in[2];
  const float* wu  = (const float*)d_in[3];
  const float* wd  = (const float*)d_in[4];
  float* y = (float*)d_out;

  char* ws = (char*)d_ws;
  size_t o = 0;
  auto alloc = [&](size_t bytes) -> char* {
    o = (o + 255) & ~(size_t)255;
    char* pp = ws + o;
    o += bytes;
    return pp;
  };
  const size_t NW = (size_t)NE * HID * DIM;
  unsigned short* wg_bf = (unsigned short*)alloc(NW * 2);
  unsigned short* wu_bf = (unsigned short*)alloc(NW * 2);
  unsigned short* wd_bf = (unsigned short*)alloc(NW * 2);
  unsigned short* x_bf  = (unsigned short*)alloc((size_t)T_TOK * DIM * 2);
  unsigned short* Hbuf  = (unsigned short*)alloc((size_t)NCAP * HID * 2);
  int*   ids      = (int*)alloc((size_t)T_TOK * 2 * 4);
  float* wts      = (float*)alloc((size_t)T_TOK * 2 * 4);
  int*   tok2slot = (int*)alloc((size_t)T_TOK * 2 * 4);
  // zero-needed region starts here:
  int*   rowmap = (int*)alloc((size_t)NCAP * 4);
  int*   counts = (int*)alloc(64);
  int*   offs   = (int*)alloc(64);
  int*   cursor = (int*)alloc(64);
  // Ybuf aliases wg_bf (dead after gemm1; gemm2 runs strictly after on same stream)
  unsigned short* Ybuf = wg_bf;

  hipMemsetAsync(rowmap, 0, (size_t)((ws + o) - (char*)rowmap), stream);

  hipFuncSetAttribute((const void*)gemm1_kernel, hipFuncAttributeMaxDynamicSharedMemorySize, 132096);
  hipFuncSetAttribute((const void*)gemm2_kernel, hipFuncAttributeMaxDynamicSharedMemorySize, 148480);

  cvtgate_kernel<<<2 * CVT_BLKS, 256, 0, stream>>>(
      wg, wu, wd, x, gwt, wg_bf, wu_bf, wd_bf, x_bf, ids, wts, counts);

  offsets_kernel<<<1, 1, 0, stream>>>(counts, offs);
  scatter_kernel<<<T_TOK / 256, 256, 0, stream>>>(ids, offs, cursor, rowmap, tok2slot);

  gemm1_kernel<<<dim3((NCAP / 256) * 22), 512, 132096, stream>>>(x_bf, wg_bf, wu_bf, rowmap, offs, Hbuf);
  gemm2_kernel<<<dim3((NCAP / 256) * 8), 512, 148480, stream>>>(Hbuf, wd_bf, offs, Ybuf);
  combine_kernel<<<T_TOK, 256, 0, stream>>>(Ybuf, tok2slot, wts, y);
}